// Round 2
// baseline (352.960 us; speedup 1.0000x reference)
//
#include <hip/hip_runtime.h>
#include <hip/hip_bf16.h>
#include <stdint.h>

// ---------------------------------------------------------------------------
// HeadAttention: Q=xq*W^T+b, K=xk*W^T+b, V=xv*W^T+b (same W,b),
// O = softmax(causal(Q K^T / 32)) V.    B=4, S=2048, E=1024, fp32 in/out.
// R7: m201-style geometry. 8 waves as 2(M)x4(N), per-wave 128x64 (MFR=8)
// or 64x64 (MFR=4).  Per 64-K tile: 4 quadrant phases, each
// {ds_read frags -> s_barrier -> lgkmcnt(0) -> setprio(1) 16 MFMA setprio(0)
//  -> s_barrier}.  Counted vmcnt (8 or 6), stage tile t+2 in phase 3
// (WAR-safe: all reads of tile t drained by phase 2's lgkm + barrier).
// T2 XOR swizzle (linear global_load_lds dest + inverse-swizzled source).
// ---------------------------------------------------------------------------

typedef __attribute__((ext_vector_type(8))) short bf16x8;
typedef __attribute__((ext_vector_type(4))) float floatx4;

#define DEVI static __device__ __forceinline__

static constexpr int S_ = 2048;
static constexpr int E_ = 1024;
static constexpr int BATCH = 4;
static constexpr int N4X = 8192 * 1024 / 4;  // float4 count per X input

DEVI unsigned short f2b(float f) {
  union { float f; unsigned u; } v; v.f = f;
  return (unsigned short)((v.u + 0x7FFFu + ((v.u >> 16) & 1u)) >> 16); // RNE
}

DEVI void async_load16(const void* g, void* l) {
  __builtin_amdgcn_global_load_lds(
      (__attribute__((address_space(1))) void*)(void*)(g),
      (__attribute__((address_space(3))) void*)(l),
      16, 0, 0);
}

// Stage a ROWSx64 bf16 tile (512 threads). LDS dest linear; the 16B chunk at
// linear slot s of row r holds logical chunk s ^ (r&7); reads undo the XOR.
template <int ROWS>
DEVI void stage(const unsigned short* __restrict__ src, int ld,
                unsigned short* ls, int tid) {
#pragma unroll
  for (int j = 0; j < ROWS / 64; ++j) {
    const int u = tid + j * 512;
    const int row = u >> 3, slot = u & 7;
    async_load16(src + row * ld + ((slot ^ (row & 7)) << 3), ls + u * 8);
  }
}

// read logical (row r, k-chunk kslot [8 bf16]) from a swizzled ROWSx64 tile
DEVI bf16x8 ldfrag(const unsigned short* ls, int r, int kslot) {
  return *(const bf16x8*)(ls + r * 64 + ((kslot ^ (r & 7)) << 3));
}

template <int N>
DEVI void read_frags(bf16x8 (&dst)[N][2], const unsigned short* ls, int row0,
                     int g) {
#pragma unroll
  for (int i = 0; i < N; ++i)
#pragma unroll
    for (int ks = 0; ks < 2; ++ks)
      dst[i][ks] = ldfrag(ls, row0 + i * 16, g + ks * 4);
}

// one quadrant: MH (M-frags) x 2 (N-frags) x 2 (K-sub) MFMAs, setprio-wrapped
template <int MH, int MO, int NO, int MFR>
DEVI void quad(bf16x8 (&a)[MH][2], bf16x8 (&b)[2][2], floatx4 (&acc)[MFR][4]) {
  __builtin_amdgcn_s_setprio(1);
#pragma unroll
  for (int mi = 0; mi < MH; ++mi)
#pragma unroll
    for (int ni = 0; ni < 2; ++ni)
#pragma unroll
      for (int ks = 0; ks < 2; ++ks)
        acc[MO + mi][NO + ni] = __builtin_amdgcn_mfma_f32_16x16x32_bf16(
            a[mi][ks], b[ni][ks], acc[MO + mi][NO + ni], 0, 0, 0);
  __builtin_amdgcn_s_setprio(0);
}

#define BARRIER asm volatile("s_barrier" ::: "memory")
#define LGKM0 asm volatile("s_waitcnt lgkmcnt(0)" ::: "memory")

// ---------------------------------------------------------------------------
// Deep-pipelined 4-phase K-loop.  BM = MFR*32 (2 M-waves), BN = 256 (4
// N-waves).  Per-thread loads per K-tile: BM/64 + 4  (=8 for MFR=8, 6 for 4).
// ---------------------------------------------------------------------------
template <int MFR>
DEVI void kloop4(const unsigned short* __restrict__ A, int lda,
                 const unsigned short* __restrict__ Bm, int ldb, int NT,
                 unsigned short* lsA, unsigned short* lsB, int tid,
                 floatx4 (&acc)[MFR][4]) {
  constexpr int BM = MFR * 32;
  constexpr int MH = MFR / 2;
  constexpr int AH = BM * 64, BH = 256 * 64;
  const int lane = tid & 63;
  const int wr = (tid >> 6) >> 2, wc = (tid >> 6) & 3;
  const int g = lane >> 4;
  const int arow0 = wr * (MFR * 16) + (lane & 15);
  const int brow0 = wc * 64 + (lane & 15);

  // prologue: tiles 0 and 1 in flight
  stage<BM>(A, lda, lsA, tid);
  stage<256>(Bm, ldb, lsB, tid);
  if (NT > 1) {
    stage<BM>(A + 64, lda, lsA + AH, tid);
    stage<256>(Bm + 64, ldb, lsB + BH, tid);
  }

  for (int t = 0; t < NT; ++t) {
    const int par = t & 1;
    if (t + 1 < NT) {
      // allow exactly tile t+1's loads to stay in flight
      if constexpr (MFR == 8)
        asm volatile("s_waitcnt vmcnt(8)" ::: "memory");
      else
        asm volatile("s_waitcnt vmcnt(6)" ::: "memory");
    } else {
      asm volatile("s_waitcnt vmcnt(0)" ::: "memory");
    }
    BARRIER;  // tile t landed for ALL waves
    const unsigned short* la = lsA + par * AH;
    const unsigned short* lb = lsB + par * BH;
    bf16x8 a[MH][2], b0[2][2], b1[2][2];
    // ph0: A-half0 + B-half0 -> C quadrant (lo,lo)
    read_frags<MH>(a, la, arow0, g);
    read_frags<2>(b0, lb, brow0, g);
    BARRIER; LGKM0;
    quad<MH, 0, 0, MFR>(a, b0, acc);
    BARRIER;
    // ph1: B-half1 -> (lo,hi)
    read_frags<2>(b1, lb, brow0 + 32, g);
    BARRIER; LGKM0;
    quad<MH, 0, 2, MFR>(a, b1, acc);
    BARRIER;
    // ph2: A-half1 -> (hi,hi)
    read_frags<MH>(a, la, arow0 + MH * 16, g);
    BARRIER; LGKM0;
    quad<MH, MH, 2, MFR>(a, b1, acc);
    BARRIER;
    // ph3: stage tile t+2 into buf par (all reads of tile t drained), (hi,lo)
    if (t + 2 < NT) {
      stage<BM>(A + (t + 2) * 64, lda, lsA + par * AH, tid);
      stage<256>(Bm + (t + 2) * 64, ldb, lsB + par * BH, tid);
    }
    quad<MH, MH, 0, MFR>(a, b0, acc);
  }
}

// fp32 -> bf16 convert: xq|xk|xv -> Xb, Wq -> Wb, one dispatch
__global__ void cvt_all(const float* __restrict__ xq,
                        const float* __restrict__ xk,
                        const float* __restrict__ xv,
                        const float* __restrict__ Wq,
                        unsigned short* __restrict__ Xb,
                        unsigned short* __restrict__ Wb) {
  int i = blockIdx.x * blockDim.x + threadIdx.x;
  const float4* src;
  ushort4* dst;
  if (i < 3 * N4X) {
    int seg = i / N4X, off = i - seg * N4X;
    const float* s = (seg == 0) ? xq : (seg == 1) ? xk : xv;
    src = (const float4*)s + off;
    dst = (ushort4*)(Xb + (size_t)seg * 8192 * 1024) + off;
  } else {
    int off = i - 3 * N4X;
    src = (const float4*)Wq + off;
    dst = (ushort4*)Wb + off;
  }
  float4 v = *src;
  ushort4 o;
  o.x = f2b(v.x); o.y = f2b(v.y); o.z = f2b(v.z); o.w = f2b(v.w);
  *dst = o;
}

// ---------------------------------------------------------------------------
// QKV: C = Xb * Wb^T + bias.  Xb = [3*8192, 1024].  256x256 tiles, 384
// blocks.  XCD x gets 12 consecutive 256-row A-panels x 4 bn.  V transposed.
// ---------------------------------------------------------------------------
__global__ __launch_bounds__(512, 2) void gemm_qkv(
    const unsigned short* __restrict__ Xb, const unsigned short* __restrict__ Wb,
    const float* __restrict__ bias, unsigned short* __restrict__ Qb,
    unsigned short* __restrict__ Kb, unsigned short* __restrict__ Vt) {
  __shared__ __align__(16) unsigned short lsA[2 * 256 * 64];
  __shared__ __align__(16) unsigned short lsB[2 * 256 * 64];
  const int l = blockIdx.x;
  const int xcd = l & 7, i = l >> 3;       // i in [0,48)
  const int bn = i & 3;                    // 256-col tile
  const int bmg = xcd * 12 + (i >> 2);     // [0,96): 256-row tile
  const unsigned short* A = Xb + (size_t)bmg * 256 * 1024;
  const unsigned short* W = Wb + (size_t)bn * 256 * 1024;
  const int tid = threadIdx.x;

  floatx4 acc[8][4] = {};
  kloop4<8>(A, 1024, W, 1024, 16, lsA, lsB, tid, acc);

  const int lane = tid & 63, wave = tid >> 6;
  const int wr = wave >> 2, wc = wave & 3;
  const int lrow = lane & 15, rb = (lane >> 4) * 4;
  const int input = bmg / 32;
  unsigned short* C = (input == 0) ? Qb : (input == 1) ? Kb : Vt;
  const int rowbase = (bmg % 32) * 256 + wr * 128;  // row within input
#pragma unroll
  for (int mi = 0; mi < 8; ++mi)
#pragma unroll
    for (int ni = 0; ni < 4; ++ni) {
      const int gcol = bn * 256 + wc * 64 + ni * 16 + lrow;
      const float bv = bias[gcol];
#pragma unroll
      for (int r = 0; r < 4; ++r) {
        const int grow = rowbase + mi * 16 + rb + r;
        const unsigned short val = f2b(acc[mi][ni][r] + bv);
        if (input == 2) {
          int b = grow >> 11, s = grow & 2047;
          C[((size_t)b * 1024 + gcol) * 2048 + s] = val;
        } else {
          C[(size_t)grow * 1024 + gcol] = val;
        }
      }
    }
}

// ---------------------------------------------------------------------------
// Scores+exp: P[z][q,k] = exp(Q.K/32) (unnorm bf16; 0 where k>q), row sums l
// via atomics.  256x256 lower-tri tiles: 36/batch, 144 blocks.
// ---------------------------------------------------------------------------
__global__ __launch_bounds__(512, 2) void gemm_scores_exp(
    const unsigned short* __restrict__ Qb,
    const unsigned short* __restrict__ Kb, unsigned short* __restrict__ P,
    float* __restrict__ lsum) {
  __shared__ __align__(16) unsigned short lsA[2 * 256 * 64];
  __shared__ __align__(16) unsigned short lsB[2 * 256 * 64];
  const int l = blockIdx.x;
  const int xcd = l & 7, i = l >> 3;  // [0,18)
  const int gid = xcd * 18 + i;       // [0,144)
  const int z = gid / 36;
  int r0 = gid % 36;
  int bm = 0;
  for (;;) { const int c = bm + 1; if (r0 < c) break; r0 -= c; ++bm; }
  const int bnn = r0;  // [0, bm]

  const unsigned short* A = Qb + ((size_t)z * S_ + bm * 256) * E_;
  const unsigned short* Bt = Kb + ((size_t)z * S_ + bnn * 256) * E_;
  const int tid = threadIdx.x;

  floatx4 acc[8][4] = {};
  kloop4<8>(A, E_, Bt, E_, 16, lsA, lsB, tid, acc);

  const int lane = tid & 63, wave = tid >> 6;
  const int wr = wave >> 2, wc = wave & 3;
  const int lrow = lane & 15, rb = (lane >> 4) * 4;
  const bool diag = (bnn == bm);
#pragma unroll
  for (int mi = 0; mi < 8; ++mi)
#pragma unroll
    for (int r = 0; r < 4; ++r) {
      const int grow = bm * 256 + wr * 128 + mi * 16 + rb + r;
      float rsum = 0.f;
#pragma unroll
      for (int ni = 0; ni < 4; ++ni) {
        const int gcol = bnn * 256 + wc * 64 + ni * 16 + lrow;
        float p = __expf(acc[mi][ni][r] * 0.03125f);
        if (diag && gcol > grow) p = 0.f;
        P[((size_t)z * S_ + grow) * S_ + gcol] = f2b(p);
        rsum += p;
      }
#pragma unroll
      for (int off = 1; off < 16; off <<= 1) rsum += __shfl_xor(rsum, off);
      if ((lane & 15) == 0) atomicAdd(&lsum[z * S_ + grow], rsum);
    }
}

// ---------------------------------------------------------------------------
// PV: out[z][q,e] = (P V) / l[q], K truncated at (bm+1)*128.  128x256 tiles,
// 256 blocks (1/CU); xcd pairs bm in {15-xcd, xcd} (17 tile-units constant).
// ---------------------------------------------------------------------------
__global__ __launch_bounds__(512, 2) void gemm_pv(
    const unsigned short* __restrict__ Pb,
    const unsigned short* __restrict__ Vt, const float* __restrict__ lsum,
    float* __restrict__ Out) {
  __shared__ __align__(16) unsigned short lsA[2 * 128 * 64];
  __shared__ __align__(16) unsigned short lsB[2 * 256 * 64];
  const int l = blockIdx.x;
  const int xcd = l & 7, i = l >> 3;  // [0,32)
  const int bn = i & 3, j = i >> 2;   // j in [0,8)
  const int z = j >> 1;
  const int bm = (j & 1) ? xcd : 15 - xcd;  // [0,16)

  const unsigned short* A = Pb + ((size_t)z * S_ + bm * 128) * S_;
  const unsigned short* Bt = Vt + ((size_t)z * E_ + bn * 256) * S_;
  float* C = Out + (size_t)z * S_ * E_;
  const int tid = threadIdx.x;
  const int NT = 2 * bm + 2;  // K-tiles of 64, covers k <= bm*128+127

  floatx4 acc[4][4] = {};
  kloop4<4>(A, S_, Bt, S_, NT, lsA, lsB, tid, acc);

  const int lane = tid & 63, wave = tid >> 6;
  const int wr = wave >> 2, wc = wave & 3;
  const int lrow = lane & 15, rb = (lane >> 4) * 4;
#pragma unroll
  for (int mi = 0; mi < 4; ++mi)
#pragma unroll
    for (int r = 0; r < 4; ++r) {
      const int grow = bm * 128 + wr * 64 + mi * 16 + rb + r;
      const float inv = 1.0f / lsum[z * S_ + grow];
#pragma unroll
      for (int ni = 0; ni < 4; ++ni) {
        const int gcol = bn * 256 + wc * 64 + ni * 16 + lrow;
        C[(size_t)grow * E_ + gcol] = acc[mi][ni][r] * inv;
      }
    }
}

// ---------------------------------------------------------------------------
extern "C" void kernel_launch(void* const* d_in, const int* in_sizes, int n_in,
                              void* d_out, int out_size, void* d_ws,
                              size_t ws_size, hipStream_t stream) {
  (void)in_sizes; (void)n_in; (void)out_size; (void)ws_size;
  const float* xq = (const float*)d_in[0];
  const float* xk = (const float*)d_in[1];
  const float* xv = (const float*)d_in[2];
  const float* Wq = (const float*)d_in[3];
  const float* bq = (const float*)d_in[4];
  // d_in[5] att_mask: exact triu(k=1) causal mask, handled analytically.
  float* out = (float*)d_out;

  // workspace (<= 114 MB used):
  //  [0,48M):  Xb (bf16 3*8192*1024) during cvt+QKV; then reused as
  //            P (bf16 4*2048*2048 = 32M) by scores/pv.
  //  [48,50M): Wb  [50,66M): Qb  [66,82M): Kb  [82,98M): Vt
  //  [98M, 98M+32K): l (fp32 row sums)
  unsigned short* base16 = (unsigned short*)d_ws;
  unsigned short* Xb = base16;
  unsigned short* P = base16;
  unsigned short* Wb = base16 + (size_t)24 * 1024 * 1024;  // +48MB
  unsigned short* Qb = Wb + (size_t)1024 * 1024;
  unsigned short* Kb = Qb + (size_t)8192 * 1024;
  unsigned short* Vt = Kb + (size_t)8192 * 1024;
  float* lsum = (float*)(Vt + (size_t)8192 * 1024);  // +98MB, 32KB

  hipMemsetAsync(lsum, 0, BATCH * S_ * sizeof(float), stream);

  const int n4tot = 3 * N4X + 1024 * 1024 / 4;
  cvt_all<<<n4tot / 256, 256, 0, stream>>>(xq, xk, xv, Wq, Xb, Wb);

  gemm_qkv<<<384, 512, 0, stream>>>(Xb, Wb, bq, Qb, Kb, Vt);
  gemm_scores_exp<<<144, 512, 0, stream>>>(Qb, Kb, P, lsum);
  gemm_pv<<<256, 512, 0, stream>>>(P, Vt, lsum, out);
}

// Round 3
// 310.128 us; speedup vs baseline: 1.1381x; 1.1381x over previous
//
#include <hip/hip_runtime.h>
#include <hip/hip_bf16.h>
#include <stdint.h>

// ---------------------------------------------------------------------------
// HeadAttention: Q=xq*W^T+b, K=xk*W^T+b, V=xv*W^T+b (same W,b),
// O = softmax(causal(Q K^T / 32)) V.    B=4, S=2048, E=1024, fp32 in/out.
// R8: scores/pv/cvt are the proven R5 kernels (2-barrier, 128x128, 256thr,
// high TLP).  qkv only is re-geometried: 256x128 block, 4 waves, per-wave
// 128x64 (MFMA:ds_read cycle ratio 155:144 vs R5's 78:96 -> MFMA-bound),
// BK=64 with XOR-swizzled LDS (BK=64 row-major would be 16-way conflict),
// same 2-barrier structure, 2 blocks/CU TLP.
// ---------------------------------------------------------------------------

typedef __attribute__((ext_vector_type(8))) short bf16x8;
typedef __attribute__((ext_vector_type(4))) float floatx4;

#define DEVI static __device__ __forceinline__

static constexpr int S_ = 2048;
static constexpr int E_ = 1024;
static constexpr int BATCH = 4;
static constexpr int N4X = 8192 * 1024 / 4;  // float4 count per X input

DEVI unsigned short f2b(float f) {
  union { float f; unsigned u; } v; v.f = f;
  return (unsigned short)((v.u + 0x7FFFu + ((v.u >> 16) & 1u)) >> 16); // RNE
}

DEVI void async_load16(const void* g, void* l) {
  __builtin_amdgcn_global_load_lds(
      (__attribute__((address_space(1))) void*)(void*)(g),
      (__attribute__((address_space(3))) void*)(l),
      16, 0, 0);
}

// ---------------- R5 helpers (scores / pv): 128x32 linear tiles ------------

// 16 MFMAs on staged 128x32 tiles. A/B frag: elem j = Mat[lane&15][(lane>>4)*8+j].
DEVI void mfma_tile(const unsigned short* lsA, const unsigned short* lsB,
                    int m0, int n0, int lrow, int lk, floatx4 (&acc)[4][4]) {
  bf16x8 af[4], bfr[4];
#pragma unroll
  for (int i = 0; i < 4; ++i)
    af[i] = *(const bf16x8*)(lsA + (m0 + i * 16 + lrow) * 32 + lk);
#pragma unroll
  for (int i = 0; i < 4; ++i)
    bfr[i] = *(const bf16x8*)(lsB + (n0 + i * 16 + lrow) * 32 + lk);
#pragma unroll
  for (int mi = 0; mi < 4; ++mi)
#pragma unroll
    for (int ni = 0; ni < 4; ++ni)
      acc[mi][ni] = __builtin_amdgcn_mfma_f32_16x16x32_bf16(
          af[mi], bfr[ni], acc[mi][ni], 0, 0, 0);
}

// stage a 128x32 bf16 tile (async DMA, 2 x 16B per thread), row stride `ld`
DEVI void stage_bf16(const unsigned short* src, unsigned short* ls, int ld,
                     int tid) {
#pragma unroll
  for (int j = 0; j < 2; ++j) {
    int t = tid + j * 256, row = t >> 2, kk = (t & 3) << 3;
    async_load16(src + (size_t)row * ld + kk, ls + t * 8);
  }
}

// ---------------- R8 qkv helpers: ROWSx64 XOR-swizzled tiles ---------------

// Stage a ROWSx64 bf16 tile with NTHR threads. LDS dest linear
// (global_load_lds requirement); the 16B chunk at linear slot s of row r
// holds logical chunk s ^ (r&7); reads undo the XOR (bank-conflict-free).
template <int ROWS, int NTHR>
DEVI void stage_sw(const unsigned short* __restrict__ src, int ld,
                   unsigned short* ls, int tid) {
#pragma unroll
  for (int j = 0; j < ROWS * 8 / NTHR; ++j) {
    const int u = tid + j * NTHR;
    const int row = u >> 3, slot = u & 7;
    async_load16(src + row * ld + ((slot ^ (row & 7)) << 3), ls + u * 8);
  }
}

// read logical (row r, k-chunk kslot [8 bf16]) from a swizzled ROWSx64 tile
DEVI bf16x8 ldfrag(const unsigned short* ls, int r, int kslot) {
  return *(const bf16x8*)(ls + r * 64 + ((kslot ^ (r & 7)) << 3));
}

// fp32 -> bf16 convert: xq|xk|xv -> Xb, Wq -> Wb, one dispatch
__global__ void cvt_all(const float* __restrict__ xq,
                        const float* __restrict__ xk,
                        const float* __restrict__ xv,
                        const float* __restrict__ Wq,
                        unsigned short* __restrict__ Xb,
                        unsigned short* __restrict__ Wb) {
  int i = blockIdx.x * blockDim.x + threadIdx.x;
  const float4* src;
  ushort4* dst;
  if (i < 3 * N4X) {
    int seg = i / N4X, off = i - seg * N4X;
    const float* s = (seg == 0) ? xq : (seg == 1) ? xk : xv;
    src = (const float4*)s + off;
    dst = (ushort4*)(Xb + (size_t)seg * 8192 * 1024) + off;
  } else {
    int off = i - 3 * N4X;  // [0, 1024*1024/4)
    src = (const float4*)Wq + off;
    dst = (ushort4*)Wb + off;
  }
  float4 v = *src;
  ushort4 o;
  o.x = f2b(v.x); o.y = f2b(v.y); o.z = f2b(v.z); o.w = f2b(v.w);
  *dst = o;
}

// ---------------------------------------------------------------------------
// QKV: C = Xb * Wb^T + bias.  Xb = [3*8192, 1024].  256x128 tiles, 768
// blocks (2/CU resident).  4 waves as 2(M)x2(N), per-wave 128x64, acc[8][4].
// Per 64-K tile: sync; stage A(256x64)+B(128x64) (12 loads/thr); sync;
// 2 x {12 ds_read_b128, 32 MFMA} per wave.  XCD x gets 12 consecutive
// 256-row A-panels x 8 bn (A-panel + whole 2MB W resident in XCD L2).
// V (input 2) stored transposed: Vt[b][e][s].
// ---------------------------------------------------------------------------
__global__ __launch_bounds__(256, 2) void gemm_qkv(
    const unsigned short* __restrict__ Xb, const unsigned short* __restrict__ Wb,
    const float* __restrict__ bias, unsigned short* __restrict__ Qb,
    unsigned short* __restrict__ Kb, unsigned short* __restrict__ Vt) {
  __shared__ __align__(16) unsigned short lsA[256 * 64];
  __shared__ __align__(16) unsigned short lsB[128 * 64];
  const int l = blockIdx.x;
  const int xcd = l & 7, i = l >> 3;     // i in [0,96)
  const int bn = i & 7;                  // 128-col tile
  const int bmg = xcd * 12 + (i >> 3);   // [0,96): 256-row tile
  const unsigned short* A = Xb + (size_t)bmg * 256 * 1024;
  const unsigned short* W = Wb + (size_t)bn * 128 * 1024;
  const int tid = threadIdx.x;
  const int lane = tid & 63, wave = tid >> 6;
  const int wr = wave >> 1, wc = wave & 1;
  const int lrow = lane & 15, g = lane >> 4;

  floatx4 acc[8][4] = {};
  for (int kt = 0; kt < 16; ++kt) {
    if (kt) __syncthreads();
    stage_sw<256, 256>(A + kt * 64, 1024, lsA, tid);
    stage_sw<128, 256>(W + kt * 64, 1024, lsB, tid);
    __syncthreads();
#pragma unroll
    for (int ks = 0; ks < 2; ++ks) {
      bf16x8 af[8], bfr[4];
#pragma unroll
      for (int mi = 0; mi < 8; ++mi)
        af[mi] = ldfrag(lsA, wr * 128 + mi * 16 + lrow, ks * 4 + g);
#pragma unroll
      for (int ni = 0; ni < 4; ++ni)
        bfr[ni] = ldfrag(lsB, wc * 64 + ni * 16 + lrow, ks * 4 + g);
#pragma unroll
      for (int mi = 0; mi < 8; ++mi)
#pragma unroll
        for (int ni = 0; ni < 4; ++ni)
          acc[mi][ni] = __builtin_amdgcn_mfma_f32_16x16x32_bf16(
              af[mi], bfr[ni], acc[mi][ni], 0, 0, 0);
    }
  }

  const int rb = (lane >> 4) * 4;  // C/D: col=lane&15, row=(lane>>4)*4+reg
  const int input = bmg >> 5;      // 32 x 256-row tiles per input (aligned)
  unsigned short* C = (input == 0) ? Qb : (input == 1) ? Kb : Vt;
  const int rowbase = (bmg & 31) * 256 + wr * 128;
#pragma unroll
  for (int mi = 0; mi < 8; ++mi)
#pragma unroll
    for (int ni = 0; ni < 4; ++ni) {
      const int gcol = bn * 128 + wc * 64 + ni * 16 + lrow;
      const float bv = bias[gcol];
#pragma unroll
      for (int r = 0; r < 4; ++r) {
        const int grow = rowbase + mi * 16 + rb + r;
        const unsigned short val = f2b(acc[mi][ni][r] + bv);
        if (input == 2) {
          int b = grow >> 11, s = grow & 2047;
          C[((size_t)b * 1024 + gcol) * 2048 + s] = val;
        } else {
          C[(size_t)grow * 1024 + gcol] = val;
        }
      }
    }
}

// ---------------------------------------------------------------------------
// Scores+exp (R5 verbatim): P[z][q,k] = exp(Q.K/32) (unnorm, bf16; 0 where
// k>q), and l[z*2048+q] += row sums (atomic).  Lower-tri 128-blocks only;
// swizzle: 768 ids, 2 XCDs/batch, groups of 8 bn share a Q tile per XCD.
// ---------------------------------------------------------------------------
__global__ __launch_bounds__(256) void gemm_scores_exp(
    const unsigned short* __restrict__ Qb,
    const unsigned short* __restrict__ Kb, unsigned short* __restrict__ P,
    float* __restrict__ lsum) {
  const int l = blockIdx.x;
  const int xcd = l & 7, k = l >> 3;
  const int m = k & 7, gl = k >> 3;
  const int gg = xcd * 12 + gl;
  const int z = gg / 24, r0 = gg % 24;
  const int bm = (r0 < 8) ? r0 : 8 + ((r0 - 8) >> 1);
  const int bn = ((r0 < 8) ? 0 : ((r0 - 8) & 1)) * 8 + m;
  if (bn > bm) return;

  __shared__ __align__(16) unsigned short lsA[2][128 * 32];
  __shared__ __align__(16) unsigned short lsB[2][128 * 32];
  const unsigned short* A = Qb + ((size_t)z * S_ + bm * 128) * E_;
  const unsigned short* Bt = Kb + ((size_t)z * S_ + bn * 128) * E_;
  const int tid = threadIdx.x;
  const int lane = tid & 63, wave = tid >> 6;
  const int m0 = (wave >> 1) * 64, n0 = (wave & 1) * 64;
  const int lrow = lane & 15, lk = (lane >> 4) * 8;

  floatx4 acc[4][4] = {};
  for (int kt = 0; kt < 16; ++kt) {
    if (kt) __syncthreads();
    stage_bf16(A + kt * 64, lsA[0], E_, tid);
    stage_bf16(A + kt * 64 + 32, lsA[1], E_, tid);
    stage_bf16(Bt + kt * 64, lsB[0], E_, tid);
    stage_bf16(Bt + kt * 64 + 32, lsB[1], E_, tid);
    __syncthreads();
    mfma_tile(lsA[0], lsB[0], m0, n0, lrow, lk, acc);
    mfma_tile(lsA[1], lsB[1], m0, n0, lrow, lk, acc);
  }

  const int rb = (lane >> 4) * 4;
  const bool diag = (bm == bn);
#pragma unroll
  for (int mi = 0; mi < 4; ++mi)
#pragma unroll
    for (int r = 0; r < 4; ++r) {
      const int grow = bm * 128 + m0 + mi * 16 + rb + r;
      float rsum = 0.f;
#pragma unroll
      for (int ni = 0; ni < 4; ++ni) {
        const int gcol = bn * 128 + n0 + ni * 16 + lrow;
        float p = __expf(acc[mi][ni][r] * 0.03125f);
        if (diag && gcol > grow) p = 0.f;
        P[((size_t)z * S_ + grow) * S_ + gcol] = f2b(p);
        rsum += p;
      }
#pragma unroll
      for (int off = 1; off < 16; off <<= 1) rsum += __shfl_xor(rsum, off);
      if ((lane & 15) == 0) atomicAdd(&lsum[z * S_ + grow], rsum);
    }
}

// ---------------------------------------------------------------------------
// PV (R5 verbatim): out[z][q,e] = (P V) / l[q], K truncated at (bm+1)*128.
// 512 blocks, pair-balanced: xcd handles bm in {15-xcd, xcd} for all 4 z.
// ---------------------------------------------------------------------------
__global__ __launch_bounds__(256) void gemm_pv(
    const unsigned short* __restrict__ Pb,
    const unsigned short* __restrict__ Vt, const float* __restrict__ lsum,
    float* __restrict__ Out) {
  __shared__ __align__(16) unsigned short lsA[2][128 * 32];
  __shared__ __align__(16) unsigned short lsB[2][128 * 32];
  const int l = blockIdx.x;
  const int xcd = l & 7, i = l >> 3;
  const int bn = i & 7, j = i >> 3;
  const int z = j >> 1;
  const int bm = (j & 1) ? xcd : 15 - xcd;

  const unsigned short* A = Pb + ((size_t)z * S_ + bm * 128) * S_;
  const unsigned short* Bt = Vt + ((size_t)z * E_ + bn * 128) * S_;
  float* C = Out + (size_t)z * S_ * E_;
  const int tid = threadIdx.x;
  const int lane = tid & 63, wave = tid >> 6;
  const int m0 = (wave >> 1) * 64, n0 = (wave & 1) * 64;
  const int lrow = lane & 15, lk = (lane >> 4) * 8;

  floatx4 acc[4][4] = {};
  const int nKK = (bm + 1) * 2;  // double-steps of 64 K
  for (int kt = 0; kt < nKK; ++kt) {
    if (kt) __syncthreads();
    stage_bf16(A + kt * 64, lsA[0], S_, tid);
    stage_bf16(A + kt * 64 + 32, lsA[1], S_, tid);
    stage_bf16(Bt + kt * 64, lsB[0], S_, tid);
    stage_bf16(Bt + kt * 64 + 32, lsB[1], S_, tid);
    __syncthreads();
    mfma_tile(lsA[0], lsB[0], m0, n0, lrow, lk, acc);
    mfma_tile(lsA[1], lsB[1], m0, n0, lrow, lk, acc);
  }

  const int rb = (lane >> 4) * 4;
#pragma unroll
  for (int mi = 0; mi < 4; ++mi)
#pragma unroll
    for (int r = 0; r < 4; ++r) {
      const int grow = bm * 128 + m0 + mi * 16 + rb + r;
      const float inv = 1.0f / lsum[z * S_ + grow];
#pragma unroll
      for (int ni = 0; ni < 4; ++ni) {
        const int gcol = bn * 128 + n0 + ni * 16 + lrow;
        C[(size_t)grow * E_ + gcol] = acc[mi][ni][r] * inv;
      }
    }
}

// ---------------------------------------------------------------------------
extern "C" void kernel_launch(void* const* d_in, const int* in_sizes, int n_in,
                              void* d_out, int out_size, void* d_ws,
                              size_t ws_size, hipStream_t stream) {
  (void)in_sizes; (void)n_in; (void)out_size; (void)ws_size;
  const float* xq = (const float*)d_in[0];
  const float* xk = (const float*)d_in[1];
  const float* xv = (const float*)d_in[2];
  const float* Wq = (const float*)d_in[3];
  const float* bq = (const float*)d_in[4];
  // d_in[5] att_mask: exact triu(k=1) causal mask, handled analytically.
  float* out = (float*)d_out;

  // workspace (<= 114 MB used):
  //  [0,48M):  Xb (bf16 3*8192*1024) during cvt+QKV; then reused as
  //            P (bf16 4*2048*2048 = 32M) by scores/pv.
  //  [48,50M): Wb  [50,66M): Qb  [66,82M): Kb  [82,98M): Vt
  //  [98M, 98M+32K): l (fp32 row sums)
  unsigned short* base16 = (unsigned short*)d_ws;
  unsigned short* Xb = base16;
  unsigned short* P = base16;
  unsigned short* Wb = base16 + (size_t)24 * 1024 * 1024;  // +48MB
  unsigned short* Qb = Wb + (size_t)1024 * 1024;
  unsigned short* Kb = Qb + (size_t)8192 * 1024;
  unsigned short* Vt = Kb + (size_t)8192 * 1024;
  float* lsum = (float*)(Vt + (size_t)8192 * 1024);  // +98MB, 32KB

  hipMemsetAsync(lsum, 0, BATCH * S_ * sizeof(float), stream);

  const int n4tot = 3 * N4X + 1024 * 1024 / 4;
  cvt_all<<<n4tot / 256, 256, 0, stream>>>(xq, xk, xv, Wq, Xb, Wb);

  gemm_qkv<<<768, 256, 0, stream>>>(Xb, Wb, bq, Qb, Kb, Vt);
  gemm_scores_exp<<<768, 256, 0, stream>>>(Qb, Kb, P, lsum);
  gemm_pv<<<512, 256, 0, stream>>>(P, Vt, lsum, out);
}